// Round 5
// baseline (539.790 us; speedup 1.0000x reference)
//
#include <hip/hip_runtime.h>
#include <hip/hip_bf16.h>
#include <math.h>

// ---------------------------------------------------------------------------
// GFA encoder forward. bf16-MFMA GEMM pipeline + parallelized attention.
// B=16, C=256, H=W=56, Hp=Wp=28, N=784, heads=8, dh=32, E=4.
// ---------------------------------------------------------------------------

#define Bdim 16
#define Cdim 256
#define Hdim 56
#define Wdim 56
#define Np 784
#define M_TOK 12544
#define M_PIX 50176

typedef __attribute__((ext_vector_type(8))) short short8;
typedef __attribute__((ext_vector_type(4))) float floatx4;

// tanh-form GELU as x*sigmoid(2z): one v_exp_f32 + one div (~7 ops vs ~25 for
// erff). |err| ~3e-4, below bf16 storage rounding of h1.
__device__ __forceinline__ float gelu_fast(float x) {
  float z = 0.7978845608028654f * fmaf(0.044715f * x, x * x, x);
  z = fminf(fmaxf(z, -15.f), 15.f);
  return x / (1.f + __expf(-2.f * z));
}

// async global->LDS, 16 bytes per lane. LDS dest must be uniform base +
// lane*16 within each wave (it is: dest = base + tid*16).
__device__ __forceinline__ void gl_lds16(const void* g, void* l) {
  __builtin_amdgcn_global_load_lds(
      (const __attribute__((address_space(1))) unsigned int*)g,
      (__attribute__((address_space(3))) unsigned int*)l, 16, 0, 0);
}

// ---------------------------------------------------------------------------
// Weight prep: cast all GEMM weights to bf16 (ct_w restructured to [rs][n][k]).
// ---------------------------------------------------------------------------
__global__ __launch_bounds__(256) void k_prep(
    const float* __restrict__ qkv_w, const float* __restrict__ proj_w,
    const float* __restrict__ pw1_w, const float* __restrict__ pw2_w,
    const float* __restrict__ ct_w, __hip_bfloat16* __restrict__ wb) {
  int i = blockIdx.x * 256 + threadIdx.x;
  if (i < 196608) { wb[i] = __float2bfloat16(qkv_w[i]); return; }
  i -= 196608;
  if (i < 65536) { (wb + 196608)[i] = __float2bfloat16(proj_w[i]); return; }
  i -= 65536;
  if (i < 262144) { (wb + 262144)[i] = __float2bfloat16(pw1_w[i]); return; }
  i -= 262144;
  if (i < 262144) { (wb + 524288)[i] = __float2bfloat16(pw2_w[i]); return; }
  i -= 262144;
  const int rs = i >> 16, rem = i & 65535, n = rem >> 8, k = rem & 255;
  (wb + 786432)[i] = __float2bfloat16(ct_w[k * 1024 + n * 4 + rs]);
}

// ---------------------------------------------------------------------------
// K1a: depthwise 3x3 + bias + residual + 2x2 avg pool. One block per (b,c).
// ---------------------------------------------------------------------------
__global__ __launch_bounds__(256) void k_pool(const float* __restrict__ x,
                                              const float* __restrict__ dww,
                                              const float* __restrict__ dwb,
                                              float* __restrict__ p) {
  __shared__ float xs[58 * 60];
  const int bid = blockIdx.x;  // b*256 + c
  const int c = bid & 255;
  const int tid = threadIdx.x;
  const float* xp = x + (size_t)bid * 3136;
  for (int i = tid; i < 58 * 60; i += 256) xs[i] = 0.f;
  __syncthreads();
  for (int i = tid; i < 3136; i += 256) {
    const int r = i / 56, cc = i % 56;
    xs[(r + 1) * 60 + (cc + 1)] = xp[i];
  }
  __syncthreads();
  float w[9];
#pragma unroll
  for (int i = 0; i < 9; i++) w[i] = dww[c * 9 + i];
  const float bias = dwb[c];
  float* pp = p + (size_t)bid * Np;
  for (int n = tid; n < Np; n += 256) {
    const int a = n / 28, bb = n % 28;
    const int r0 = 2 * a, c0 = 2 * bb;
    float acc = 0.f;
#pragma unroll
    for (int pi = 0; pi < 2; pi++)
#pragma unroll
      for (int pj = 0; pj < 2; pj++) {
        float conv = bias;
#pragma unroll
        for (int rr = 0; rr < 3; rr++)
#pragma unroll
          for (int ss = 0; ss < 3; ss++)
            conv = fmaf(xs[(r0 + pi + rr) * 60 + c0 + pj + ss], w[rr * 3 + ss],
                        conv);
        acc += conv + xs[(r0 + pi + 1) * 60 + (c0 + pj + 1)];
      }
    pp[n] = acc * 0.25f;
  }
}

// ---------------------------------------------------------------------------
// K1b: transpose p [B,C,N] -> t [B,N,C] with LayerNorm over C. bf16 out.
// ---------------------------------------------------------------------------
__global__ __launch_bounds__(256) void k_lnt(const float* __restrict__ p,
                                             const float* __restrict__ g1,
                                             const float* __restrict__ b1,
                                             __hip_bfloat16* __restrict__ t) {
  __shared__ float xs[256][65];
  __shared__ float red[4][64][2];
  __shared__ float ms[64][2];
  const int n0 = blockIdx.x * 64;
  const int b = blockIdx.y;
  const int tid = threadIdx.x;
  const int lane = tid & 63, grp = tid >> 6;
  const int n = n0 + lane;
  const bool nok = (n < Np);
  float s1 = 0.f, s2 = 0.f;
  for (int it = 0; it < 64; it++) {
    const int c = grp * 64 + it;
    const float v = nok ? p[((size_t)b * Cdim + c) * Np + n] : 0.f;
    xs[c][lane] = v;
    s1 += v;
    s2 += v * v;
  }
  red[grp][lane][0] = s1;
  red[grp][lane][1] = s2;
  __syncthreads();
  if (tid < 64) {
    const float a1 =
        red[0][tid][0] + red[1][tid][0] + red[2][tid][0] + red[3][tid][0];
    const float a2 =
        red[0][tid][1] + red[1][tid][1] + red[2][tid][1] + red[3][tid][1];
    const float m = a1 * (1.f / 256.f);
    const float var = a2 * (1.f / 256.f) - m * m;
    ms[tid][0] = m;
    ms[tid][1] = rsqrtf(var + 1e-6f);
  }
  __syncthreads();
  const float gg = g1[tid], bb = b1[tid];
  const int nlim = (Np - n0 < 64) ? (Np - n0) : 64;
  for (int tok = 0; tok < nlim; tok++) {
    const float v = (xs[tid][tok] - ms[tok][0]) * ms[tok][1] * gg + bb;
    t[((size_t)b * Np + n0 + tok) * Cdim + tid] = __float2bfloat16(v);
  }
}

// ---------------------------------------------------------------------------
// bf16 MFMA GEMM: C = A[M,K] @ W[N,K]^T + bias. 128x128 tile, BK=32,
// 4 waves 2x2, 16x16x32 MFMA, global_load_lds(16B) staging (m97 structure).
// Epilogue: LDS-transpose (reuse As) -> coalesced dwordx4 stores, 4 phases
// of 32 rows. Round-4 lesson: 64 scalar 2B stores/thread caused ~2.4x write
// amplification + RMW fetches (WRITE 60.6 MB vs 25.7 ideal).
// EPI: 0 bf16 store; 1 +resid bf16; 2 GELU bf16; 3 ct-quadrant scatter bf16.
// ---------------------------------------------------------------------------
template <int EPI>
__global__ __launch_bounds__(256) void mm_bf16(
    const __hip_bfloat16* __restrict__ A, const __hip_bfloat16* __restrict__ W,
    const float* __restrict__ bias, __hip_bfloat16* __restrict__ C, int M,
    int N, int K, const __hip_bfloat16* __restrict__ resid) {
  __shared__ __align__(16) short As[128 * 32];
  __shared__ __align__(16) short Bs[128 * 32];
  const int tid = threadIdx.x;
  const int w = tid >> 6, l = tid & 63;
  const int lane16 = l & 15, quad = l >> 4;
  const int wr = w >> 1, wc = w & 1;
  const int m0 = blockIdx.y * 128, n0 = blockIdx.x * 128;
  if constexpr (EPI == 3) W += (size_t)blockIdx.z * 65536;

  // thread tid stages 16B chunks tid and tid+256 (rows gm, gm+64)
  const int gm = tid >> 2, gc = tid & 3;
  const __hip_bfloat16* Ag0 = A + (size_t)(m0 + gm) * K + gc * 8;
  const __hip_bfloat16* Ag1 = Ag0 + (size_t)64 * K;
  const __hip_bfloat16* Bg0 = W + (size_t)(n0 + gm) * K + gc * 8;
  const __hip_bfloat16* Bg1 = Bg0 + (size_t)64 * K;
  short* Asl0 = &As[tid * 8];
  short* Asl1 = &As[(tid + 256) * 8];
  short* Bsl0 = &Bs[tid * 8];
  short* Bsl1 = &Bs[(tid + 256) * 8];

  floatx4 acc[4][4];
#pragma unroll
  for (int i = 0; i < 4; i++)
#pragma unroll
    for (int j = 0; j < 4; j++) acc[i][j] = (floatx4)0.f;

  for (int k0 = 0; k0 < K; k0 += 32) {
    gl_lds16(Ag0 + k0, Asl0);
    gl_lds16(Ag1 + k0, Asl1);
    gl_lds16(Bg0 + k0, Bsl0);
    gl_lds16(Bg1 + k0, Bsl1);
    __syncthreads();
    short8 af[4], bfr[4];
#pragma unroll
    for (int i = 0; i < 4; i++) {
      const int ma = wr * 64 + i * 16 + lane16;
      af[i] = *(const short8*)&As[ma * 32 + quad * 8];
      const int nb = wc * 64 + i * 16 + lane16;
      bfr[i] = *(const short8*)&Bs[nb * 32 + quad * 8];
    }
#pragma unroll
    for (int i = 0; i < 4; i++)
#pragma unroll
      for (int j = 0; j < 4; j++)
        acc[i][j] = __builtin_amdgcn_mfma_f32_16x16x32_bf16(af[i], bfr[j],
                                                            acc[i][j], 0, 0, 0);
    __syncthreads();
  }

  // ---- epilogue: 4 phases x 32 rows through LDS (reuse As: 32x128 bf16) ----
  const float4 bi = {bias[n0 + wc * 64 + 0 * 16 + lane16],
                     bias[n0 + wc * 64 + 1 * 16 + lane16],
                     bias[n0 + wc * 64 + 2 * 16 + lane16],
                     bias[n0 + wc * 64 + 3 * 16 + lane16]};
#pragma unroll
  for (int rg = 0; rg < 4; rg++) {
    if (wr == (rg >> 1)) {
#pragma unroll
      for (int il = 0; il < 2; il++) {
        const int i = (rg & 1) * 2 + il;
#pragma unroll
        for (int j = 0; j < 4; j++) {
          const float bj = (j == 0) ? bi.x : (j == 1) ? bi.y : (j == 2) ? bi.z : bi.w;
          const int col = n0 + wc * 64 + j * 16 + lane16;
#pragma unroll
          for (int r = 0; r < 4; r++) {
            const int rl = il * 16 + quad * 4 + r;
            float v = acc[i][j][r] + bj;
            if constexpr (EPI == 1) {
              const int row = m0 + rg * 32 + rl;
              v += __bfloat162float(resid[(size_t)row * N + col]);
            }
            if constexpr (EPI == 2) v = gelu_fast(v);
            __hip_bfloat16 hv = __float2bfloat16(v);
            As[rl * 128 + wc * 64 + j * 16 + lane16] = *(short*)&hv;
          }
        }
      }
    }
    __syncthreads();
    {
      const int rl = tid >> 3, cb = (tid & 7) * 16;
      const int4 d0 = *(const int4*)&As[rl * 128 + cb];
      const int4 d1 = *(const int4*)&As[rl * 128 + cb + 8];
      const int row = m0 + rg * 32 + rl;
      if constexpr (EPI == 3) {
        const int bI = row / Np, nr = row % Np;
        const int aa = nr / 28, cc = nr % 28;
        const int rr = blockIdx.z >> 1, ss = blockIdx.z & 1;
        const size_t o =
            (((size_t)(bI * Hdim + 2 * aa + rr)) * Wdim + 2 * cc + ss) * Cdim +
            n0 + cb;
        *(int4*)((unsigned short*)C + o) = d0;
        *(int4*)((unsigned short*)C + o + 8) = d1;
      } else {
        const size_t o = (size_t)row * N + n0 + cb;
        *(int4*)((unsigned short*)C + o) = d0;
        *(int4*)((unsigned short*)C + o + 8) = d1;
      }
    }
    __syncthreads();
  }
}

// ---------------------------------------------------------------------------
// Attention stage 1: partial Gram (32x32) + partial q/k norms per
// (bh, 112-token chunk). part row: [0..1023]=S, [1024..1055]=qn, [1056..]=kn.
// ---------------------------------------------------------------------------
__global__ __launch_bounds__(256) void k_gram(
    const __hip_bfloat16* __restrict__ qkv, float* __restrict__ part) {
  __shared__ float qs[32][113], ks[32][113];
  const int c = blockIdx.x;   // 0..6
  const int bh = blockIdx.y;  // 0..127
  const int b = bh >> 3, h = bh & 7;
  const int tid = threadIdx.x;
  const size_t base = (size_t)b * Np * 768 + h * 32;
  const int n0 = c * 112;
  const int ld = tid & 31, lj = tid >> 5;
#pragma unroll
  for (int it = 0; it < 14; it++) {
    const int jt = lj + it * 8;
    const size_t off = base + (size_t)(n0 + jt) * 768 + ld;
    qs[ld][jt] = __bfloat162float(qkv[off]);
    ks[ld][jt] = __bfloat162float(qkv[off + 256]);
  }
  __syncthreads();
  const int d = tid >> 3, e4 = tid & 7;
  float s4[4] = {0.f, 0.f, 0.f, 0.f};
#pragma unroll 4
  for (int j = 0; j < 112; j++) {
    const float qv = qs[d][j];
#pragma unroll
    for (int u = 0; u < 4; u++) s4[u] = fmaf(qv, ks[e4 * 4 + u][j], s4[u]);
  }
  float* pp = part + ((size_t)bh * 7 + c) * 1088;
  *(float4*)&pp[d * 32 + e4 * 4] = *(float4*)s4;
  if (tid < 64) {
    float nrm = 0.f;
    if (tid < 32) {
      for (int j = 0; j < 112; j++) { const float q = qs[tid][j]; nrm = fmaf(q, q, nrm); }
      pp[1024 + tid] = nrm;
    } else {
      for (int j = 0; j < 112; j++) { const float k = ks[tid - 32][j]; nrm = fmaf(k, k, nrm); }
      pp[1056 + (tid - 32)] = nrm;
    }
  }
}

// ---------------------------------------------------------------------------
// Attention stage 2: reduce partials, normalize, temp, mask, softmax -> P.
// ---------------------------------------------------------------------------
__global__ __launch_bounds__(256) void k_soft(const float* __restrict__ part,
                                              const float* __restrict__ mask_u,
                                              const float* __restrict__ temp,
                                              float* __restrict__ P) {
  const int bh = blockIdx.x;
  const int h = bh & 7;
  const int tid = threadIdx.x;
  const int d = tid >> 3, e4 = tid & 7;
  float4 S = {0.f, 0.f, 0.f, 0.f};
  float qn = 0.f;
  float4 kn = {0.f, 0.f, 0.f, 0.f};
  for (int c = 0; c < 7; c++) {
    const float* pp = part + ((size_t)bh * 7 + c) * 1088;
    const float4 s = *(const float4*)&pp[d * 32 + e4 * 4];
    S.x += s.x; S.y += s.y; S.z += s.z; S.w += s.w;
    qn += pp[1024 + d];
    const float4 k4 = *(const float4*)&pp[1056 + e4 * 4];
    kn.x += k4.x; kn.y += k4.y; kn.z += k4.z; kn.w += k4.w;
  }
  const float tmp = temp[h];
  const float qd = fmaxf(sqrtf(qn), 1e-12f);
  float val[4];
  val[0] = S.x / (qd * fmaxf(sqrtf(kn.x), 1e-12f)) * tmp;
  val[1] = S.y / (qd * fmaxf(sqrtf(kn.y), 1e-12f)) * tmp;
  val[2] = S.z / (qd * fmaxf(sqrtf(kn.z), 1e-12f)) * tmp;
  val[3] = S.w / (qd * fmaxf(sqrtf(kn.w), 1e-12f)) * tmp;
  const float4 mu = *(const float4*)&mask_u[(size_t)bh * 1024 + d * 32 + e4 * 4];
  if (mu.x < 0.2f) val[0] -= 1e12f;
  if (mu.y < 0.2f) val[1] -= 1e12f;
  if (mu.z < 0.2f) val[2] -= 1e12f;
  if (mu.w < 0.2f) val[3] -= 1e12f;
  float mx = fmaxf(fmaxf(val[0], val[1]), fmaxf(val[2], val[3]));
  mx = fmaxf(mx, __shfl_xor(mx, 1));
  mx = fmaxf(mx, __shfl_xor(mx, 2));
  mx = fmaxf(mx, __shfl_xor(mx, 4));
  float ex[4];
  float sum = 0.f;
#pragma unroll
  for (int u = 0; u < 4; u++) { ex[u] = expf(val[u] - mx); sum += ex[u]; }
  sum += __shfl_xor(sum, 1);
  sum += __shfl_xor(sum, 2);
  sum += __shfl_xor(sum, 4);
  const float inv = 1.0f / sum;
  float4 out;
  out.x = ex[0] * inv; out.y = ex[1] * inv; out.z = ex[2] * inv; out.w = ex[3] * inv;
  *(float4*)&P[(size_t)bh * 1024 + d * 32 + e4 * 4] = out;
}

// ---------------------------------------------------------------------------
// Attention stage 3: out = P @ v per (bh, 98-token chunk) -> attout[B,N,C].
// ---------------------------------------------------------------------------
__global__ __launch_bounds__(256) void k_pv(const float* __restrict__ P,
                                            const __hip_bfloat16* __restrict__ qkv,
                                            __hip_bfloat16* __restrict__ attout) {
  __shared__ float vs[32][99];
  const int ch = blockIdx.x;  // 0..7
  const int bh = blockIdx.y;
  const int b = bh >> 3, h = bh & 7;
  const int tid = threadIdx.x;
  const int d = tid & 31, jrow = tid >> 5;
  const int n0 = ch * 98;
  const size_t vbase = (size_t)b * Np * 768 + h * 32 + 512;
  const size_t obase = (size_t)b * Np * Cdim + h * 32;

  float Pr[32];
  const float* Pw = P + (size_t)bh * 1024 + d * 32;
#pragma unroll
  for (int e4 = 0; e4 < 8; e4++) {
    const float4 p4 = *(const float4*)&Pw[e4 * 4];
    Pr[e4 * 4 + 0] = p4.x; Pr[e4 * 4 + 1] = p4.y;
    Pr[e4 * 4 + 2] = p4.z; Pr[e4 * 4 + 3] = p4.w;
  }
#pragma unroll
  for (int it = 0; it < 13; it++) {
    const int jt = jrow + it * 8;
    if (jt < 98) vs[d][jt] = __bfloat162float(qkv[vbase + (size_t)(n0 + jt) * 768 + d]);
  }
  __syncthreads();
#pragma unroll
  for (int it = 0; it < 13; it++) {
    const int jt = jrow + it * 8;
    if (jt < 98) {
      float o = 0.f;
#pragma unroll
      for (int e = 0; e < 32; e++) o = fmaf(Pr[e], vs[e][jt], o);
      attout[obase + (size_t)(n0 + jt) * Cdim + d] = __float2bfloat16(o);
    }
  }
}

// ---------------------------------------------------------------------------
// LN2: per NHWC row of u (bf16), write normalized bf16. One wave per row.
// ---------------------------------------------------------------------------
__global__ __launch_bounds__(256) void k_ln2(const __hip_bfloat16* __restrict__ u,
                                             const float* __restrict__ g2,
                                             const float* __restrict__ b2,
                                             __hip_bfloat16* __restrict__ o) {
  const int row = blockIdx.x * 4 + (threadIdx.x >> 6);
  const int lane = threadIdx.x & 63;
  const unsigned short* ur = (const unsigned short*)u + (size_t)row * Cdim;
  const ushort4 raw = *(const ushort4*)(ur + lane * 4);
  float v[4];
  v[0] = __bfloat162float(*(const __hip_bfloat16*)&raw.x);
  v[1] = __bfloat162float(*(const __hip_bfloat16*)&raw.y);
  v[2] = __bfloat162float(*(const __hip_bfloat16*)&raw.z);
  v[3] = __bfloat162float(*(const __hip_bfloat16*)&raw.w);
  float s1 = v[0] + v[1] + v[2] + v[3];
  float s2 = v[0] * v[0] + v[1] * v[1] + v[2] * v[2] + v[3] * v[3];
#pragma unroll
  for (int off = 32; off > 0; off >>= 1) {
    s1 += __shfl_down(s1, off);
    s2 += __shfl_down(s2, off);
  }
  s1 = __shfl(s1, 0);
  s2 = __shfl(s2, 0);
  const float m = s1 * (1.f / 256.f);
  const float var = s2 * (1.f / 256.f) - m * m;
  const float rstd = rsqrtf(var + 1e-6f);
  const float4 g = *(const float4*)&g2[lane * 4];
  const float4 bb = *(const float4*)&b2[lane * 4];
  ushort4 ov;
  __hip_bfloat16 t0 = __float2bfloat16((v[0] - m) * rstd * g.x + bb.x);
  __hip_bfloat16 t1 = __float2bfloat16((v[1] - m) * rstd * g.y + bb.y);
  __hip_bfloat16 t2 = __float2bfloat16((v[2] - m) * rstd * g.z + bb.z);
  __hip_bfloat16 t3 = __float2bfloat16((v[3] - m) * rstd * g.w + bb.w);
  ov.x = *(unsigned short*)&t0;
  ov.y = *(unsigned short*)&t1;
  ov.z = *(unsigned short*)&t2;
  ov.w = *(unsigned short*)&t3;
  *(ushort4*)((unsigned short*)o + (size_t)row * Cdim + lane * 4) = ov;
}

// ---------------------------------------------------------------------------
// Final: out[b,c,h,w] = x[b,c,h,w] + y_bf16[b,h,w,c]  (LDS transpose tile)
// ---------------------------------------------------------------------------
__global__ __launch_bounds__(256) void k_final(const float* __restrict__ x,
                                               const __hip_bfloat16* __restrict__ y,
                                               float* __restrict__ out) {
  __shared__ float tile[64][65];
  const int hw0 = blockIdx.x * 64;
  const int c0 = blockIdx.y * 64;
  const int b = blockIdx.z;
  const int tid = threadIdx.x;
  {
    const int ci = tid & 63;
    const int hwB = tid >> 6;
#pragma unroll
    for (int it = 0; it < 16; it++) {
      const int hwi = hwB + it * 4;
      tile[hwi][ci] =
          __bfloat162float(y[((size_t)b * 3136 + hw0 + hwi) * Cdim + c0 + ci]);
    }
  }
  __syncthreads();
  {
    const int hwi = tid & 63;
    const int cB = tid >> 6;
#pragma unroll
    for (int it = 0; it < 16; it++) {
      const int ci = cB + it * 4;
      const size_t o = ((size_t)(b * Cdim + c0 + ci)) * 3136 + hw0 + hwi;
      out[o] = x[o] + tile[hwi][ci];
    }
  }
}

// ---------------------------------------------------------------------------
// Host launcher
// ---------------------------------------------------------------------------
extern "C" void kernel_launch(void* const* d_in, const int* in_sizes, int n_in,
                              void* d_out, int out_size, void* d_ws,
                              size_t ws_size, hipStream_t stream) {
  const float* x      = (const float*)d_in[0];
  const float* mask_u = (const float*)d_in[1];
  const float* dw_w   = (const float*)d_in[2];
  const float* dw_b   = (const float*)d_in[3];
  const float* g1     = (const float*)d_in[4];
  const float* b1     = (const float*)d_in[5];
  const float* qkv_w  = (const float*)d_in[6];
  const float* qkv_b  = (const float*)d_in[7];
  const float* temp   = (const float*)d_in[8];
  const float* proj_w = (const float*)d_in[9];
  const float* proj_b = (const float*)d_in[10];
  const float* ct_w   = (const float*)d_in[11];
  const float* ct_b   = (const float*)d_in[12];
  const float* g2     = (const float*)d_in[13];
  const float* b2     = (const float*)d_in[14];
  const float* pw1_w  = (const float*)d_in[15];
  const float* pw1_b  = (const float*)d_in[16];
  const float* pw2_w  = (const float*)d_in[17];
  const float* pw2_b  = (const float*)d_in[18];

  char* wsb = (char*)d_ws;
  // byte-offset layout with lifetime aliasing (peak ~105 MB):
  __hip_bfloat16* u      = (__hip_bfloat16*)(wsb + 0);          // 25,690,112
  __hip_bfloat16* rbuf   = (__hip_bfloat16*)(wsb + 25690112);   //  6,422,528
  float*          p      = (float*)        (wsb + 32112640);    // 12,845,056
  __hip_bfloat16* t      = (__hip_bfloat16*)(wsb + 44957696);   //  6,422,528
  __hip_bfloat16* ln2    = (__hip_bfloat16*)(wsb + 25690112);   // (after r/p/t die)
  __hip_bfloat16* qkvb   = (__hip_bfloat16*)(wsb + 51380224);   // 19,267,584
  __hip_bfloat16* h1     = (__hip_bfloat16*)(wsb + 51380224);   // (after qkv dies)
  __hip_bfloat16* attout = (__hip_bfloat16*)(wsb + 77070336);   //  6,422,528
  __hip_bfloat16* y      = (__hip_bfloat16*)(wsb + 77070336);   // (after attout dies)
  __hip_bfloat16* wb     = (__hip_bfloat16*)(wsb + 102760448);  //  2,097,152
  // attention scratch aliases the dead p region (p dies after k_lnt):
  float* part = (float*)(wsb + 32112640);        // 896*1088 floats = 3.9 MB
  float* Pws  = part + 974848;                   // 128*1024 floats = 0.5 MB
  float* out = (float*)d_out;

  const __hip_bfloat16* wqkv = wb;
  const __hip_bfloat16* wproj = wb + 196608;
  const __hip_bfloat16* wpw1 = wb + 262144;
  const __hip_bfloat16* wpw2 = wb + 524288;
  const __hip_bfloat16* wct = wb + 786432;

  // 0) weights -> bf16
  k_prep<<<dim3(4096), 256, 0, stream>>>(qkv_w, proj_w, pw1_w, pw2_w, ct_w, wb);
  // 1) dw conv + residual + pool -> p
  k_pool<<<dim3(4096), 256, 0, stream>>>(x, dw_w, dw_b, p);
  // 2) transpose + LN1 -> t
  k_lnt<<<dim3(13, Bdim), 256, 0, stream>>>(p, g1, b1, t);
  // 3) qkv GEMM
  mm_bf16<0><<<dim3(6, 98), 256, 0, stream>>>(t, wqkv, qkv_b, qkvb, M_TOK, 768,
                                              256, nullptr);
  // 4) attention: gram partials -> softmax P -> P@V
  k_gram<<<dim3(7, 128), 256, 0, stream>>>(qkvb, part);
  k_soft<<<dim3(128), 256, 0, stream>>>(part, mask_u, temp, Pws);
  k_pv<<<dim3(8, 128), 256, 0, stream>>>(Pws, qkvb, attout);
  // 5) proj GEMM + t residual -> r
  mm_bf16<1><<<dim3(2, 98), 256, 0, stream>>>(attout, wproj, proj_b, rbuf,
                                              M_TOK, 256, 256, t);
  // 6) conv-transpose (4 quadrant GEMMs) -> u (NHWC bf16)
  mm_bf16<3><<<dim3(2, 98, 4), 256, 0, stream>>>(rbuf, wct, ct_b, u, M_TOK, 256,
                                                 256, nullptr);
  // 7) LN2 -> ln2
  k_ln2<<<dim3(M_PIX / 4), 256, 0, stream>>>(u, g2, b2, ln2);
  // 8) MLP in 4 chunks
  for (int ch = 0; ch < 4; ch++) {
    const __hip_bfloat16* lc = ln2 + (size_t)ch * M_TOK * Cdim;
    __hip_bfloat16* yc = y + (size_t)ch * M_TOK * Cdim;
    mm_bf16<2><<<dim3(8, 98), 256, 0, stream>>>(lc, wpw1, pw1_b, h1, M_TOK,
                                                1024, 256, nullptr);
    mm_bf16<0><<<dim3(2, 98), 256, 0, stream>>>(h1, wpw2, pw2_b, yc, M_TOK, 256,
                                                1024, nullptr);
  }
  // 9) out = x + transpose(y)
  k_final<<<dim3(49, 4, Bdim), 256, 0, stream>>>(x, y, out);
}

// Round 7
// 379.690 us; speedup vs baseline: 1.4217x; 1.4217x over previous
//
#include <hip/hip_runtime.h>
#include <hip/hip_bf16.h>
#include <math.h>

// ---------------------------------------------------------------------------
// GFA encoder forward. bf16-MFMA GEMM pipeline (single-barrier dbuf K-loop)
// + parallelized attention. B=16, C=256, H=W=56, N=784, heads=8, dh=32, E=4.
// Round-6 bug: de-chunked MLP h1 needs 102.7 MB, layout reserved 25.7 MB ->
// clobbered y and the bf16 weights. Fixed layout (total 237.7 MB < 268 MB).
// ---------------------------------------------------------------------------

#define Bdim 16
#define Cdim 256
#define Hdim 56
#define Wdim 56
#define Np 784
#define M_TOK 12544
#define M_PIX 50176

typedef __attribute__((ext_vector_type(8))) short short8;
typedef __attribute__((ext_vector_type(4))) float floatx4;

__device__ __forceinline__ float gelu_fast(float x) {
  float z = 0.7978845608028654f * fmaf(0.044715f * x, x * x, x);
  z = fminf(fmaxf(z, -15.f), 15.f);
  return x / (1.f + __expf(-2.f * z));
}

__device__ __forceinline__ float bf2f(short s) {
  unsigned int u = ((unsigned int)(unsigned short)s) << 16;
  return __builtin_bit_cast(float, u);
}
__device__ __forceinline__ short f2bf(float f) {
  __hip_bfloat16 h = __float2bfloat16(f);
  return *(short*)&h;
}

// async global->LDS, 16 bytes per lane (dest = wave-uniform base + lane*16).
__device__ __forceinline__ void gl_lds16(const void* g, void* l) {
  __builtin_amdgcn_global_load_lds(
      (const __attribute__((address_space(1))) unsigned int*)g,
      (__attribute__((address_space(3))) unsigned int*)l, 16, 0, 0);
}

// ---------------------------------------------------------------------------
// Weight prep: cast all GEMM weights to bf16 (ct_w restructured to [rs][n][k]).
// ---------------------------------------------------------------------------
__global__ __launch_bounds__(256) void k_prep(
    const float* __restrict__ qkv_w, const float* __restrict__ proj_w,
    const float* __restrict__ pw1_w, const float* __restrict__ pw2_w,
    const float* __restrict__ ct_w, __hip_bfloat16* __restrict__ wb) {
  int i = blockIdx.x * 256 + threadIdx.x;
  if (i < 196608) { wb[i] = __float2bfloat16(qkv_w[i]); return; }
  i -= 196608;
  if (i < 65536) { (wb + 196608)[i] = __float2bfloat16(proj_w[i]); return; }
  i -= 65536;
  if (i < 262144) { (wb + 262144)[i] = __float2bfloat16(pw1_w[i]); return; }
  i -= 262144;
  if (i < 262144) { (wb + 524288)[i] = __float2bfloat16(pw2_w[i]); return; }
  i -= 262144;
  const int rs = i >> 16, rem = i & 65535, n = rem >> 8, k = rem & 255;
  (wb + 786432)[i] = __float2bfloat16(ct_w[k * 1024 + n * 4 + rs]);
}

// ---------------------------------------------------------------------------
// K1a: depthwise 3x3 + bias + residual + 2x2 avg pool. One block per (b,c).
// ---------------------------------------------------------------------------
__global__ __launch_bounds__(256) void k_pool(const float* __restrict__ x,
                                              const float* __restrict__ dww,
                                              const float* __restrict__ dwb,
                                              float* __restrict__ p) {
  __shared__ float xs[58 * 60];
  const int bid = blockIdx.x;  // b*256 + c
  const int c = bid & 255;
  const int tid = threadIdx.x;
  const float* xp = x + (size_t)bid * 3136;
  for (int i = tid; i < 58 * 60; i += 256) xs[i] = 0.f;
  __syncthreads();
  for (int i = tid; i < 3136; i += 256) {
    const int r = i / 56, cc = i % 56;
    xs[(r + 1) * 60 + (cc + 1)] = xp[i];
  }
  __syncthreads();
  float w[9];
#pragma unroll
  for (int i = 0; i < 9; i++) w[i] = dww[c * 9 + i];
  const float bias = dwb[c];
  float* pp = p + (size_t)bid * Np;
  for (int n = tid; n < Np; n += 256) {
    const int a = n / 28, bb = n % 28;
    const int r0 = 2 * a, c0 = 2 * bb;
    float acc = 0.f;
#pragma unroll
    for (int pi = 0; pi < 2; pi++)
#pragma unroll
      for (int pj = 0; pj < 2; pj++) {
        float conv = bias;
#pragma unroll
        for (int rr = 0; rr < 3; rr++)
#pragma unroll
          for (int ss = 0; ss < 3; ss++)
            conv = fmaf(xs[(r0 + pi + rr) * 60 + c0 + pj + ss], w[rr * 3 + ss],
                        conv);
        acc += conv + xs[(r0 + pi + 1) * 60 + (c0 + pj + 1)];
      }
    pp[n] = acc * 0.25f;
  }
}

// ---------------------------------------------------------------------------
// K1b: transpose p [B,C,N] -> t [B,N,C] with LayerNorm over C. bf16 out.
// ---------------------------------------------------------------------------
__global__ __launch_bounds__(256) void k_lnt(const float* __restrict__ p,
                                             const float* __restrict__ g1,
                                             const float* __restrict__ b1,
                                             __hip_bfloat16* __restrict__ t) {
  __shared__ float xs[256][65];
  __shared__ float red[4][64][2];
  __shared__ float ms[64][2];
  const int n0 = blockIdx.x * 64;
  const int b = blockIdx.y;
  const int tid = threadIdx.x;
  const int lane = tid & 63, grp = tid >> 6;
  const int n = n0 + lane;
  const bool nok = (n < Np);
  float s1 = 0.f, s2 = 0.f;
  for (int it = 0; it < 64; it++) {
    const int c = grp * 64 + it;
    const float v = nok ? p[((size_t)b * Cdim + c) * Np + n] : 0.f;
    xs[c][lane] = v;
    s1 += v;
    s2 += v * v;
  }
  red[grp][lane][0] = s1;
  red[grp][lane][1] = s2;
  __syncthreads();
  if (tid < 64) {
    const float a1 =
        red[0][tid][0] + red[1][tid][0] + red[2][tid][0] + red[3][tid][0];
    const float a2 =
        red[0][tid][1] + red[1][tid][1] + red[2][tid][1] + red[3][tid][1];
    const float m = a1 * (1.f / 256.f);
    const float var = a2 * (1.f / 256.f) - m * m;
    ms[tid][0] = m;
    ms[tid][1] = rsqrtf(var + 1e-6f);
  }
  __syncthreads();
  const float gg = g1[tid], bb = b1[tid];
  const int nlim = (Np - n0 < 64) ? (Np - n0) : 64;
  for (int tok = 0; tok < nlim; tok++) {
    const float v = (xs[tid][tok] - ms[tok][0]) * ms[tok][1] * gg + bb;
    t[((size_t)b * Np + n0 + tok) * Cdim + tid] = __float2bfloat16(v);
  }
}

// ---------------------------------------------------------------------------
// bf16 MFMA GEMM: C = A[M,K] @ W[N,K]^T + bias. 128x128 tile, BK=32, 4 waves
// 2x2, 16x16x32 MFMA. Single-barrier pipelined K-loop with dbuf LDS: loads
// issued after barrier k land during MFMA phase and are drained at barrier
// k+1 (explicit vmcnt(0) + the compiler's own barrier drain).
// Epilogue: one 32KB LDS round-trip, bias/act/resid in vectorized readback.
// EPI: 0 bf16 store; 1 +resid bf16; 2 GELU bf16; 3 ct-quadrant scatter bf16.
// ---------------------------------------------------------------------------
template <int EPI>
__global__ __launch_bounds__(256) void mm_bf16(
    const __hip_bfloat16* __restrict__ A, const __hip_bfloat16* __restrict__ W,
    const float* __restrict__ bias, __hip_bfloat16* __restrict__ C, int M,
    int N, int K, const __hip_bfloat16* __restrict__ resid) {
  __shared__ __align__(16) short LS[16384];  // dbuf 2x(A 4096 + B 4096) shorts
  const int tid = threadIdx.x;
  const int w = tid >> 6, l = tid & 63;
  const int lane16 = l & 15, quad = l >> 4;
  const int wr = w >> 1, wc = w & 1;
  const int m0 = blockIdx.y * 128, n0 = blockIdx.x * 128;
  if constexpr (EPI == 3) W += (size_t)blockIdx.z * 65536;

  const int gm = tid >> 2, gc = tid & 3;
  const __hip_bfloat16* Ag0 = A + (size_t)(m0 + gm) * K + gc * 8;
  const __hip_bfloat16* Ag1 = Ag0 + (size_t)64 * K;
  const __hip_bfloat16* Bg0 = W + (size_t)(n0 + gm) * K + gc * 8;
  const __hip_bfloat16* Bg1 = Bg0 + (size_t)64 * K;

  floatx4 acc[4][4];
#pragma unroll
  for (int i = 0; i < 4; i++)
#pragma unroll
    for (int j = 0; j < 4; j++) acc[i][j] = (floatx4)0.f;

  // prologue: stage k=0 into buffer 0
  gl_lds16(Ag0, &LS[tid * 8]);
  gl_lds16(Ag1, &LS[(tid + 256) * 8]);
  gl_lds16(Bg0, &LS[4096 + tid * 8]);
  gl_lds16(Bg1, &LS[4096 + (tid + 256) * 8]);

  int buf = 0;
  for (int k0 = 0; k0 < K; k0 += 32) {
    // drain own outstanding global_load_lds before the barrier (insurance;
    // the compiler's __syncthreads lowering also emits vmcnt(0)).
    asm volatile("s_waitcnt vmcnt(0)" ::: "memory");
    __syncthreads();
    const int nb = buf ^ 1;
    if (k0 + 32 < K) {
      short* d = &LS[nb * 8192];
      gl_lds16(Ag0 + k0 + 32, &d[tid * 8]);
      gl_lds16(Ag1 + k0 + 32, &d[(tid + 256) * 8]);
      gl_lds16(Bg0 + k0 + 32, &d[4096 + tid * 8]);
      gl_lds16(Bg1 + k0 + 32, &d[4096 + (tid + 256) * 8]);
    }
    const short* Ab = &LS[buf * 8192];
    const short* Bb = Ab + 4096;
    short8 af[4], bfr[4];
#pragma unroll
    for (int i = 0; i < 4; i++) {
      af[i] = *(const short8*)&Ab[(wr * 64 + i * 16 + lane16) * 32 + quad * 8];
      bfr[i] = *(const short8*)&Bb[(wc * 64 + i * 16 + lane16) * 32 + quad * 8];
    }
#pragma unroll
    for (int i = 0; i < 4; i++)
#pragma unroll
      for (int j = 0; j < 4; j++)
        acc[i][j] = __builtin_amdgcn_mfma_f32_16x16x32_bf16(af[i], bfr[j],
                                                            acc[i][j], 0, 0, 0);
    buf = nb;
  }
  asm volatile("s_waitcnt vmcnt(0)" ::: "memory");
  __syncthreads();  // all MFMA reads done before LS reuse

  // ---- epilogue: acc -> LS as 128x128 bf16 tile ----
#pragma unroll
  for (int i = 0; i < 4; i++) {
#pragma unroll
    for (int j = 0; j < 4; j++) {
      const int col_l = wc * 64 + j * 16 + lane16;
#pragma unroll
      for (int r = 0; r < 4; r++) {
        const int row_l = wr * 64 + i * 16 + quad * 4 + r;
        LS[row_l * 128 + col_l] = f2bf(acc[i][j][r]);
      }
    }
  }
  __syncthreads();
  // readback: 8 phases, linear (conflict-free LDS, 256B-coalesced stores)
#pragma unroll
  for (int p = 0; p < 8; p++) {
    const int idx = tid * 8 + p * 2048;  // short index
    const int r = idx >> 7, col = idx & 127;
    const short8 d = *(const short8*)&LS[idx];
    float v[8];
#pragma unroll
    for (int e = 0; e < 8; e++) v[e] = bf2f(d[e]);
    const float4 b0 = *(const float4*)&bias[n0 + col];
    const float4 b1v = *(const float4*)&bias[n0 + col + 4];
    v[0] += b0.x; v[1] += b0.y; v[2] += b0.z; v[3] += b0.w;
    v[4] += b1v.x; v[5] += b1v.y; v[6] += b1v.z; v[7] += b1v.w;
    const int row = m0 + r;
    if constexpr (EPI == 1) {
      const short8 rs =
          *(const short8*)((const short*)resid + (size_t)row * N + n0 + col);
#pragma unroll
      for (int e = 0; e < 8; e++) v[e] += bf2f(rs[e]);
    }
    if constexpr (EPI == 2) {
#pragma unroll
      for (int e = 0; e < 8; e++) v[e] = gelu_fast(v[e]);
    }
    short8 o;
#pragma unroll
    for (int e = 0; e < 8; e++) o[e] = f2bf(v[e]);
    if constexpr (EPI == 3) {
      const int bI = row / Np, nr = row % Np;
      const int aa = nr / 28, cc = nr % 28;
      const int rr = blockIdx.z >> 1, ss = blockIdx.z & 1;
      const size_t off =
          (((size_t)(bI * Hdim + 2 * aa + rr)) * Wdim + 2 * cc + ss) * Cdim +
          n0 + col;
      *(short8*)((short*)C + off) = o;
    } else {
      *(short8*)((short*)C + (size_t)row * N + n0 + col) = o;
    }
  }
}

// ---------------------------------------------------------------------------
// Attention stage 1: partial Gram (32x32) + partial q/k norms per
// (bh, 112-token chunk). part row: [0..1023]=S, [1024..1055]=qn, [1056..]=kn.
// ---------------------------------------------------------------------------
__global__ __launch_bounds__(256) void k_gram(
    const __hip_bfloat16* __restrict__ qkv, float* __restrict__ part) {
  __shared__ float qs[32][113], ks[32][113];
  const int c = blockIdx.x;   // 0..6
  const int bh = blockIdx.y;  // 0..127
  const int b = bh >> 3, h = bh & 7;
  const int tid = threadIdx.x;
  const size_t base = (size_t)b * Np * 768 + h * 32;
  const int n0 = c * 112;
  const int ld = tid & 31, lj = tid >> 5;
#pragma unroll
  for (int it = 0; it < 14; it++) {
    const int jt = lj + it * 8;
    const size_t off = base + (size_t)(n0 + jt) * 768 + ld;
    qs[ld][jt] = __bfloat162float(qkv[off]);
    ks[ld][jt] = __bfloat162float(qkv[off + 256]);
  }
  __syncthreads();
  const int d = tid >> 3, e4 = tid & 7;
  float s4[4] = {0.f, 0.f, 0.f, 0.f};
#pragma unroll 4
  for (int j = 0; j < 112; j++) {
    const float qv = qs[d][j];
#pragma unroll
    for (int u = 0; u < 4; u++) s4[u] = fmaf(qv, ks[e4 * 4 + u][j], s4[u]);
  }
  float* pp = part + ((size_t)bh * 7 + c) * 1088;
  *(float4*)&pp[d * 32 + e4 * 4] = *(float4*)s4;
  if (tid < 64) {
    float nrm = 0.f;
    if (tid < 32) {
      for (int j = 0; j < 112; j++) { const float q = qs[tid][j]; nrm = fmaf(q, q, nrm); }
      pp[1024 + tid] = nrm;
    } else {
      for (int j = 0; j < 112; j++) { const float k = ks[tid - 32][j]; nrm = fmaf(k, k, nrm); }
      pp[1056 + (tid - 32)] = nrm;
    }
  }
}

// ---------------------------------------------------------------------------
// Attention stage 2: reduce partials, normalize, temp, mask, softmax -> P.
// ---------------------------------------------------------------------------
__global__ __launch_bounds__(256) void k_soft(const float* __restrict__ part,
                                              const float* __restrict__ mask_u,
                                              const float* __restrict__ temp,
                                              float* __restrict__ P) {
  const int bh = blockIdx.x;
  const int h = bh & 7;
  const int tid = threadIdx.x;
  const int d = tid >> 3, e4 = tid & 7;
  float4 S = {0.f, 0.f, 0.f, 0.f};
  float qn = 0.f;
  float4 kn = {0.f, 0.f, 0.f, 0.f};
  for (int c = 0; c < 7; c++) {
    const float* pp = part + ((size_t)bh * 7 + c) * 1088;
    const float4 s = *(const float4*)&pp[d * 32 + e4 * 4];
    S.x += s.x; S.y += s.y; S.z += s.z; S.w += s.w;
    qn += pp[1024 + d];
    const float4 k4 = *(const float4*)&pp[1056 + e4 * 4];
    kn.x += k4.x; kn.y += k4.y; kn.z += k4.z; kn.w += k4.w;
  }
  const float tmp = temp[h];
  const float qd = fmaxf(sqrtf(qn), 1e-12f);
  float val[4];
  val[0] = S.x / (qd * fmaxf(sqrtf(kn.x), 1e-12f)) * tmp;
  val[1] = S.y / (qd * fmaxf(sqrtf(kn.y), 1e-12f)) * tmp;
  val[2] = S.z / (qd * fmaxf(sqrtf(kn.z), 1e-12f)) * tmp;
  val[3] = S.w / (qd * fmaxf(sqrtf(kn.w), 1e-12f)) * tmp;
  const float4 mu = *(const float4*)&mask_u[(size_t)bh * 1024 + d * 32 + e4 * 4];
  if (mu.x < 0.2f) val[0] -= 1e12f;
  if (mu.y < 0.2f) val[1] -= 1e12f;
  if (mu.z < 0.2f) val[2] -= 1e12f;
  if (mu.w < 0.2f) val[3] -= 1e12f;
  float mx = fmaxf(fmaxf(val[0], val[1]), fmaxf(val[2], val[3]));
  mx = fmaxf(mx, __shfl_xor(mx, 1));
  mx = fmaxf(mx, __shfl_xor(mx, 2));
  mx = fmaxf(mx, __shfl_xor(mx, 4));
  float ex[4];
  float sum = 0.f;
#pragma unroll
  for (int u = 0; u < 4; u++) { ex[u] = expf(val[u] - mx); sum += ex[u]; }
  sum += __shfl_xor(sum, 1);
  sum += __shfl_xor(sum, 2);
  sum += __shfl_xor(sum, 4);
  const float inv = 1.0f / sum;
  float4 out;
  out.x = ex[0] * inv; out.y = ex[1] * inv; out.z = ex[2] * inv; out.w = ex[3] * inv;
  *(float4*)&P[(size_t)bh * 1024 + d * 32 + e4 * 4] = out;
}

// ---------------------------------------------------------------------------
// Attention stage 3: out = P @ v per (bh, 98-token chunk) -> attout[B,N,C].
// ---------------------------------------------------------------------------
__global__ __launch_bounds__(256) void k_pv(const float* __restrict__ P,
                                            const __hip_bfloat16* __restrict__ qkv,
                                            __hip_bfloat16* __restrict__ attout) {
  __shared__ float vs[32][99];
  const int ch = blockIdx.x;  // 0..7
  const int bh = blockIdx.y;
  const int b = bh >> 3, h = bh & 7;
  const int tid = threadIdx.x;
  const int d = tid & 31, jrow = tid >> 5;
  const int n0 = ch * 98;
  const size_t vbase = (size_t)b * Np * 768 + h * 32 + 512;
  const size_t obase = (size_t)b * Np * Cdim + h * 32;

  float Pr[32];
  const float* Pw = P + (size_t)bh * 1024 + d * 32;
#pragma unroll
  for (int e4 = 0; e4 < 8; e4++) {
    const float4 p4 = *(const float4*)&Pw[e4 * 4];
    Pr[e4 * 4 + 0] = p4.x; Pr[e4 * 4 + 1] = p4.y;
    Pr[e4 * 4 + 2] = p4.z; Pr[e4 * 4 + 3] = p4.w;
  }
#pragma unroll
  for (int it = 0; it < 13; it++) {
    const int jt = jrow + it * 8;
    if (jt < 98) vs[d][jt] = __bfloat162float(qkv[vbase + (size_t)(n0 + jt) * 768 + d]);
  }
  __syncthreads();
#pragma unroll
  for (int it = 0; it < 13; it++) {
    const int jt = jrow + it * 8;
    if (jt < 98) {
      float o = 0.f;
#pragma unroll
      for (int e = 0; e < 32; e++) o = fmaf(Pr[e], vs[e][jt], o);
      attout[obase + (size_t)(n0 + jt) * Cdim + d] = __float2bfloat16(o);
    }
  }
}

// ---------------------------------------------------------------------------
// LN2: per NHWC row of u (bf16), write normalized bf16. One wave per row.
// ---------------------------------------------------------------------------
__global__ __launch_bounds__(256) void k_ln2(const __hip_bfloat16* __restrict__ u,
                                             const float* __restrict__ g2,
                                             const float* __restrict__ b2,
                                             __hip_bfloat16* __restrict__ o) {
  const int row = blockIdx.x * 4 + (threadIdx.x >> 6);
  const int lane = threadIdx.x & 63;
  const unsigned short* ur = (const unsigned short*)u + (size_t)row * Cdim;
  const ushort4 raw = *(const ushort4*)(ur + lane * 4);
  float v[4];
  v[0] = __bfloat162float(*(const __hip_bfloat16*)&raw.x);
  v[1] = __bfloat162float(*(const __hip_bfloat16*)&raw.y);
  v[2] = __bfloat162float(*(const __hip_bfloat16*)&raw.z);
  v[3] = __bfloat162float(*(const __hip_bfloat16*)&raw.w);
  float s1 = v[0] + v[1] + v[2] + v[3];
  float s2 = v[0] * v[0] + v[1] * v[1] + v[2] * v[2] + v[3] * v[3];
#pragma unroll
  for (int off = 32; off > 0; off >>= 1) {
    s1 += __shfl_down(s1, off);
    s2 += __shfl_down(s2, off);
  }
  s1 = __shfl(s1, 0);
  s2 = __shfl(s2, 0);
  const float m = s1 * (1.f / 256.f);
  const float var = s2 * (1.f / 256.f) - m * m;
  const float rstd = rsqrtf(var + 1e-6f);
  const float4 g = *(const float4*)&g2[lane * 4];
  const float4 bb = *(const float4*)&b2[lane * 4];
  ushort4 ov;
  __hip_bfloat16 t0 = __float2bfloat16((v[0] - m) * rstd * g.x + bb.x);
  __hip_bfloat16 t1 = __float2bfloat16((v[1] - m) * rstd * g.y + bb.y);
  __hip_bfloat16 t2 = __float2bfloat16((v[2] - m) * rstd * g.z + bb.z);
  __hip_bfloat16 t3 = __float2bfloat16((v[3] - m) * rstd * g.w + bb.w);
  ov.x = *(unsigned short*)&t0;
  ov.y = *(unsigned short*)&t1;
  ov.z = *(unsigned short*)&t2;
  ov.w = *(unsigned short*)&t3;
  *(ushort4*)((unsigned short*)o + (size_t)row * Cdim + lane * 4) = ov;
}

// ---------------------------------------------------------------------------
// Final: out[b,c,h,w] = x[b,c,h,w] + y_bf16[b,h,w,c]  (LDS transpose tile)
// ---------------------------------------------------------------------------
__global__ __launch_bounds__(256) void k_final(const float* __restrict__ x,
                                               const __hip_bfloat16* __restrict__ y,
                                               float* __restrict__ out) {
  __shared__ float tile[64][65];
  const int hw0 = blockIdx.x * 64;
  const int c0 = blockIdx.y * 64;
  const int b = blockIdx.z;
  const int tid = threadIdx.x;
  {
    const int ci = tid & 63;
    const int hwB = tid >> 6;
#pragma unroll
    for (int it = 0; it < 16; it++) {
      const int hwi = hwB + it * 4;
      tile[hwi][ci] =
          __bfloat162float(y[((size_t)b * 3136 + hw0 + hwi) * Cdim + c0 + ci]);
    }
  }
  __syncthreads();
  {
    const int hwi = tid & 63;
    const int cB = tid >> 6;
#pragma unroll
    for (int it = 0; it < 16; it++) {
      const int ci = cB + it * 4;
      const size_t o = ((size_t)(b * Cdim + c0 + ci)) * 3136 + hw0 + hwi;
      out[o] = x[o] + tile[hwi][ci];
    }
  }
}

// ---------------------------------------------------------------------------
// Host launcher
// ---------------------------------------------------------------------------
extern "C" void kernel_launch(void* const* d_in, const int* in_sizes, int n_in,
                              void* d_out, int out_size, void* d_ws,
                              size_t ws_size, hipStream_t stream) {
  const float* x      = (const float*)d_in[0];
  const float* mask_u = (const float*)d_in[1];
  const float* dw_w   = (const float*)d_in[2];
  const float* dw_b   = (const float*)d_in[3];
  const float* g1     = (const float*)d_in[4];
  const float* b1     = (const float*)d_in[5];
  const float* qkv_w  = (const float*)d_in[6];
  const float* qkv_b  = (const float*)d_in[7];
  const float* temp   = (const float*)d_in[8];
  const float* proj_w = (const float*)d_in[9];
  const float* proj_b = (const float*)d_in[10];
  const float* ct_w   = (const float*)d_in[11];
  const float* ct_b   = (const float*)d_in[12];
  const float* g2     = (const float*)d_in[13];
  const float* b2     = (const float*)d_in[14];
  const float* pw1_w  = (const float*)d_in[15];
  const float* pw1_b  = (const float*)d_in[16];
  const float* pw2_w  = (const float*)d_in[17];
  const float* pw2_b  = (const float*)d_in[18];

  char* wsb = (char*)d_ws;
  // flat layout, no aliasing; h1 now full-size (round-6 fix). total 237.7 MB.
  float*          p      = (float*)        (wsb + 0);           //  12,845,056
  __hip_bfloat16* t      = (__hip_bfloat16*)(wsb + 12845056);   //   6,422,528
  __hip_bfloat16* qkvb   = (__hip_bfloat16*)(wsb + 19267584);   //  19,267,584
  float*          part   = (float*)        (wsb + 38535168);    //   3,899,392
  float*          Pws    = (float*)        (wsb + 42434560);    //     524,288
  __hip_bfloat16* attout = (__hip_bfloat16*)(wsb + 42958848);   //   6,422,528
  __hip_bfloat16* rbuf   = (__hip_bfloat16*)(wsb + 49381376);   //   6,422,528
  __hip_bfloat16* u      = (__hip_bfloat16*)(wsb + 55803904);   //  25,690,112
  __hip_bfloat16* ln2    = (__hip_bfloat16*)(wsb + 81494016);   //  25,690,112
  __hip_bfloat16* h1     = (__hip_bfloat16*)(wsb + 107184128);  // 102,760,448
  __hip_bfloat16* y      = (__hip_bfloat16*)(wsb + 209944576);  //  25,690,112
  __hip_bfloat16* wb     = (__hip_bfloat16*)(wsb + 235634688);  //   2,097,152
  float* out = (float*)d_out;

  const __hip_bfloat16* wqkv = wb;
  const __hip_bfloat16* wproj = wb + 196608;
  const __hip_bfloat16* wpw1 = wb + 262144;
  const __hip_bfloat16* wpw2 = wb + 524288;
  const __hip_bfloat16* wct = wb + 786432;

  // 0) weights -> bf16
  k_prep<<<dim3(4096), 256, 0, stream>>>(qkv_w, proj_w, pw1_w, pw2_w, ct_w, wb);
  // 1) dw conv + residual + pool -> p
  k_pool<<<dim3(4096), 256, 0, stream>>>(x, dw_w, dw_b, p);
  // 2) transpose + LN1 -> t
  k_lnt<<<dim3(13, Bdim), 256, 0, stream>>>(p, g1, b1, t);
  // 3) qkv GEMM
  mm_bf16<0><<<dim3(6, 98), 256, 0, stream>>>(t, wqkv, qkv_b, qkvb, M_TOK, 768,
                                              256, nullptr);
  // 4) attention: gram partials -> softmax P -> P@V
  k_gram<<<dim3(7, 128), 256, 0, stream>>>(qkvb, part);
  k_soft<<<dim3(128), 256, 0, stream>>>(part, mask_u, temp, Pws);
  k_pv<<<dim3(8, 128), 256, 0, stream>>>(Pws, qkvb, attout);
  // 5) proj GEMM + t residual -> rbuf
  mm_bf16<1><<<dim3(2, 98), 256, 0, stream>>>(attout, wproj, proj_b, rbuf,
                                              M_TOK, 256, 256, t);
  // 6) conv-transpose (4 quadrant GEMMs) -> u (NHWC bf16)
  mm_bf16<3><<<dim3(2, 98, 4), 256, 0, stream>>>(rbuf, wct, ct_b, u, M_TOK, 256,
                                                 256, nullptr);
  // 7) LN2 -> ln2
  k_ln2<<<dim3(M_PIX / 4), 256, 0, stream>>>(u, g2, b2, ln2);
  // 8) MLP, de-chunked single dispatches
  mm_bf16<2><<<dim3(8, 392), 256, 0, stream>>>(ln2, wpw1, pw1_b, h1, M_PIX,
                                               1024, 256, nullptr);
  mm_bf16<0><<<dim3(2, 392), 256, 0, stream>>>(h1, wpw2, pw2_b, y, M_PIX, 256,
                                               1024, nullptr);
  // 9) out = x + transpose(y)
  k_final<<<dim3(49, 4, Bdim), 256, 0, stream>>>(x, y, out);
}